// Round 1
// baseline (169.643 us; speedup 1.0000x reference)
//
#include <hip/hip_runtime.h>

// QTT 3D sampling: out[n] = e_{d0} C0 · C1[d1] · ... · C7[d7] for 4096 samples.
// Round 1: one block per sample, fp32, LDS-held state vector, K-split across waves.
// Core shapes: (r_l, 8, r_{l+1}) with ranks 1,8,64,256,256,256,64,8,1.
// C_l[r][d][s] = C_l[r*(8*r_out) + d*r_out + s].

__global__ __launch_bounds__(256) void qtt_sample_kernel(
    const float* __restrict__ C0, const float* __restrict__ C1,
    const float* __restrict__ C2, const float* __restrict__ C3,
    const float* __restrict__ C4, const float* __restrict__ C5,
    const float* __restrict__ C6, const float* __restrict__ C7,
    const int* __restrict__ coords, float* __restrict__ out)
{
    const int n = blockIdx.x;
    const int t = threadIdx.x;

    __shared__ float vA[256];
    __shared__ float vB[256];
    __shared__ float4 red[256];   // per-thread float4 partials for K-split reduce

    const int x = coords[3 * n + 0];
    const int y = coords[3 * n + 1];
    const int z = coords[3 * n + 2];

#define DIGIT(l) (4 * ((x >> (7 - (l))) & 1) + 2 * ((y >> (7 - (l))) & 1) + ((z >> (7 - (l))) & 1))

    // ---- stage 0: v = C0[0, d0, :]  (8) ----
    if (t < 8) vA[t] = C0[DIGIT(0) * 8 + t];
    __syncthreads();

    // ---- stage 1: 8 -> 64 ----  C1[r*512 + d*64 + s]
    if (t < 64) {
        const float* b = C1 + DIGIT(1) * 64 + t;
        float acc = 0.f;
#pragma unroll
        for (int r = 0; r < 8; ++r) acc += vA[r] * b[r * 512];
        vB[t] = acc;
    }
    __syncthreads();

    // ---- stage 2: 64 -> 256 (vB -> vA) ----  C2[r*2048 + d*256 + s]
    {
        const int cg = t & 63, kp = t >> 6;               // 64 col-groups x 4 K-parts
        const float4* b = (const float4*)(C2 + DIGIT(2) * 256) + cg;
        float4 acc = {0.f, 0.f, 0.f, 0.f};
#pragma unroll 8
        for (int r = kp * 16; r < kp * 16 + 16; ++r) {
            const float vr = vB[r];
            const float4 c = b[r * 512];                  // row stride 2048 floats
            acc.x += vr * c.x; acc.y += vr * c.y; acc.z += vr * c.z; acc.w += vr * c.w;
        }
        red[t] = acc;
    }
    __syncthreads();
    {
        const int cg = t >> 2, j = t & 3;
        float s = 0.f;
#pragma unroll
        for (int kp = 0; kp < 4; ++kp) s += ((const float*)&red[kp * 64 + cg])[j];
        vA[t] = s;
    }
    __syncthreads();

    // ---- stage 3: 256 -> 256 (vA -> vB) ----  C3[r*2048 + d*256 + s]
    {
        const int cg = t & 63, kp = t >> 6;               // K-part covers 64 rows
        const float4* b = (const float4*)(C3 + DIGIT(3) * 256) + cg;
        float4 acc = {0.f, 0.f, 0.f, 0.f};
#pragma unroll 8
        for (int r = kp * 64; r < kp * 64 + 64; ++r) {
            const float vr = vA[r];
            const float4 c = b[r * 512];
            acc.x += vr * c.x; acc.y += vr * c.y; acc.z += vr * c.z; acc.w += vr * c.w;
        }
        red[t] = acc;
    }
    __syncthreads();
    {
        const int cg = t >> 2, j = t & 3;
        float s = 0.f;
#pragma unroll
        for (int kp = 0; kp < 4; ++kp) s += ((const float*)&red[kp * 64 + cg])[j];
        vB[t] = s;
    }
    __syncthreads();

    // ---- stage 4: 256 -> 256 (vB -> vA) ----  C4[r*2048 + d*256 + s]
    {
        const int cg = t & 63, kp = t >> 6;
        const float4* b = (const float4*)(C4 + DIGIT(4) * 256) + cg;
        float4 acc = {0.f, 0.f, 0.f, 0.f};
#pragma unroll 8
        for (int r = kp * 64; r < kp * 64 + 64; ++r) {
            const float vr = vB[r];
            const float4 c = b[r * 512];
            acc.x += vr * c.x; acc.y += vr * c.y; acc.z += vr * c.z; acc.w += vr * c.w;
        }
        red[t] = acc;
    }
    __syncthreads();
    {
        const int cg = t >> 2, j = t & 3;
        float s = 0.f;
#pragma unroll
        for (int kp = 0; kp < 4; ++kp) s += ((const float*)&red[kp * 64 + cg])[j];
        vA[t] = s;
    }
    __syncthreads();

    // ---- stage 5: 256 -> 64 (vA -> vB) ----  C5[r*512 + d*64 + s]
    {
        const int cg = t & 15, kp = t >> 4;               // 16 col-groups x 16 K-parts
        const float4* b = (const float4*)(C5 + DIGIT(5) * 64) + cg;
        float4 acc = {0.f, 0.f, 0.f, 0.f};
#pragma unroll 8
        for (int r = kp * 16; r < kp * 16 + 16; ++r) {
            const float vr = vA[r];
            const float4 c = b[r * 128];                  // row stride 512 floats
            acc.x += vr * c.x; acc.y += vr * c.y; acc.z += vr * c.z; acc.w += vr * c.w;
        }
        red[t] = acc;
    }
    __syncthreads();
    if (t < 64) {
        const int cg = t >> 2, j = t & 3;
        float s = 0.f;
#pragma unroll
        for (int kp = 0; kp < 16; ++kp) s += ((const float*)&red[kp * 16 + cg])[j];
        vB[t] = s;
    }
    __syncthreads();

    // ---- stage 6: 64 -> 8 (vB -> vA) ----  C6[r*64 + d*8 + s]
    if (t < 64) {
        const int s6 = t & 7, kp = t >> 3;                // 8 cols x 8 K-parts
        const float* b = C6 + DIGIT(6) * 8 + s6;
        float acc = 0.f;
#pragma unroll
        for (int r = kp * 8; r < kp * 8 + 8; ++r) acc += vB[r] * b[r * 64];
        ((float*)red)[t] = acc;
    }
    __syncthreads();
    if (t < 8) {
        float s = 0.f;
#pragma unroll
        for (int kp = 0; kp < 8; ++kp) s += ((const float*)red)[kp * 8 + t];
        vA[t] = s;
    }
    __syncthreads();

    // ---- stage 7: 8 -> 1 ----  C7[r*8 + d]  (shape (8,8,1))
    if (t == 0) {
        const int d7 = DIGIT(7);
        float acc = 0.f;
#pragma unroll
        for (int r = 0; r < 8; ++r) acc += vA[r] * C7[r * 8 + d7];
        out[n] = acc;
    }
#undef DIGIT
}

extern "C" void kernel_launch(void* const* d_in, const int* in_sizes, int n_in,
                              void* d_out, int out_size, void* d_ws, size_t ws_size,
                              hipStream_t stream) {
    const float* C0 = (const float*)d_in[0];
    const float* C1 = (const float*)d_in[1];
    const float* C2 = (const float*)d_in[2];
    const float* C3 = (const float*)d_in[3];
    const float* C4 = (const float*)d_in[4];
    const float* C5 = (const float*)d_in[5];
    const float* C6 = (const float*)d_in[6];
    const float* C7 = (const float*)d_in[7];
    const int* coords = (const int*)d_in[8];
    float* out = (float*)d_out;

    const int n_samples = in_sizes[8] / 3;   // coords_xyz is (N, 3)
    qtt_sample_kernel<<<n_samples, 256, 0, stream>>>(C0, C1, C2, C3, C4, C5, C6, C7,
                                                     coords, out);
}